// Round 1
// baseline (903.618 us; speedup 1.0000x reference)
//
#include <hip/hip_runtime.h>

#define N_TOK 4096
#define DIM   1024
#define HID   4096
#define NSLOT 8192          // N_TOK * TOPK
#define TOTROWS 12288       // NSLOT + N_TOK (shared expert appended)

typedef __bf16 bf16x8 __attribute__((ext_vector_type(8)));
typedef float  floatx4 __attribute__((ext_vector_type(4)));
typedef unsigned short us8 __attribute__((ext_vector_type(8)));
typedef unsigned short us4v __attribute__((ext_vector_type(4)));

static __device__ __forceinline__ unsigned short f2bf(float f) {
    unsigned u = __builtin_bit_cast(unsigned, f);
    unsigned r = 0x7fffu + ((u >> 16) & 1u);
    return (unsigned short)((u + r) >> 16);
}

// ---------------- x -> bf16 ----------------
__global__ void cvt_x_kernel(const float* __restrict__ x, unsigned short* __restrict__ xb) {
    int i = (blockIdx.x * 256 + threadIdx.x) * 4;
    float4 v = *(const float4*)(x + i);
    us4v o; o[0] = f2bf(v.x); o[1] = f2bf(v.y); o[2] = f2bf(v.z); o[3] = f2bf(v.w);
    *(us4v*)(xb + i) = o;
}

// ---------------- router: fp64 logits, top-2, counts ----------------
__global__ void router_kernel(const float* __restrict__ x, const float* __restrict__ Wr,
                              int* __restrict__ topk_idx, float* __restrict__ topk_w,
                              int* __restrict__ counts) {
    int lane = threadIdx.x & 63;
    int wave = threadIdx.x >> 6;
    int t = blockIdx.x * 4 + wave;
    const float* xr = x + (size_t)t * DIM;
    double acc[8];
    #pragma unroll
    for (int e = 0; e < 8; ++e) acc[e] = 0.0;
    #pragma unroll
    for (int it = 0; it < DIM / 64; ++it) {
        int d = it * 64 + lane;
        float xv = xr[d];
        const float* wr = Wr + (size_t)d * 8;
        float4 w0 = *(const float4*)wr;
        float4 w1 = *(const float4*)(wr + 4);
        acc[0] += (double)xv * w0.x; acc[1] += (double)xv * w0.y;
        acc[2] += (double)xv * w0.z; acc[3] += (double)xv * w0.w;
        acc[4] += (double)xv * w1.x; acc[5] += (double)xv * w1.y;
        acc[6] += (double)xv * w1.z; acc[7] += (double)xv * w1.w;
    }
    #pragma unroll
    for (int e = 0; e < 8; ++e) {
        #pragma unroll
        for (int off = 32; off > 0; off >>= 1)
            acc[e] += __shfl_xor(acc[e], off, 64);
    }
    if (lane == 0) {
        float p[8];
        #pragma unroll
        for (int e = 0; e < 8; ++e) p[e] = 1.0f / (1.0f + expf(-(float)acc[e]));
        int i0 = 0;
        for (int e = 1; e < 8; ++e) if (p[e] > p[i0]) i0 = e;        // ties -> lower idx
        int i1 = (i0 == 0) ? 1 : 0;
        for (int e = 0; e < 8; ++e) if (e != i0 && p[e] > p[i1]) i1 = e;
        float s = p[i0] + p[i1] + 1e-6f;
        topk_idx[t * 2]     = i0;
        topk_idx[t * 2 + 1] = i1;
        topk_w[t * 2]       = p[i0] / s;
        topk_w[t * 2 + 1]   = p[i1] / s;
        atomicAdd(&counts[i0], 1);
        atomicAdd(&counts[i1], 1);
    }
}

// ---------------- tiny exclusive scan over 8 experts ----------------
__global__ void scan_kernel(const int* __restrict__ counts, int* __restrict__ offsets) {
    if (threadIdx.x == 0) {
        int off = 0;
        for (int e = 0; e < 8; ++e) { offsets[e] = off; off += counts[e]; }
        offsets[8] = off;   // == NSLOT
    }
}

// ---------------- slot assignment (compacted per-expert lists) ----------------
__global__ void assign_kernel(const int* __restrict__ topk_idx, const float* __restrict__ topk_w,
                              const int* __restrict__ offsets, int* __restrict__ cursors,
                              int* __restrict__ slot_token, float* __restrict__ slot_w,
                              int* __restrict__ token_slot) {
    int t = blockIdx.x * 256 + threadIdx.x;
    #pragma unroll
    for (int j = 0; j < 2; ++j) {
        int e = topk_idx[t * 2 + j];
        int pos = atomicAdd(&cursors[e], 1);
        int s = offsets[e] + pos;
        slot_token[s] = t;
        slot_w[s] = topk_w[t * 2 + j];
        token_slot[t * 2 + j] = s;
    }
    // shared expert = "expert 8": all tokens, weight 1
    slot_token[NSLOT + t] = t;
    slot_w[NSLOT + t] = 1.0f;
}

// ---------------- grouped GEMM: 128x128x32 tiles, mfma_f32_16x16x32_bf16 ----------------
// MODE 0: up   — A = xb gathered via slot_token, epilogue sq_relu, bf16 out (hg)
// MODE 1: down — A = hg rows direct, epilogue *slot_w, fp32 out (yg)
template<int MODE>
__global__ void moe_gemm(const unsigned short* __restrict__ Abase,
                         const float* __restrict__ Wexp,
                         const float* __restrict__ Wsh,
                         unsigned short* __restrict__ Hout,
                         float* __restrict__ Yout,
                         const int* __restrict__ slot_token,
                         const float* __restrict__ slot_w,
                         const int* __restrict__ counts,
                         const int* __restrict__ offsets,
                         int K, int Nn, int lda)
{
    const int e   = blockIdx.z;
    const int cnt = (e == 8) ? N_TOK : counts[e];
    const int mt  = blockIdx.y;
    if (mt * 128 >= cnt) return;            // uniform early-exit (worst-case grid)
    const int nt  = blockIdx.x;
    const int off = offsets[e];
    const float* Bp = (e == 8) ? Wsh : (Wexp + (size_t)e * K * Nn);

    // stride 40 (=80B): 16B-aligned ds_read_b128, <=2-way bank aliasing
    __shared__ unsigned short As[128 * 40];
    __shared__ unsigned short Bs[128 * 40];

    const int t    = threadIdx.x;
    const int lane = t & 63;
    const int wave = t >> 6;
    const int wm   = wave >> 1, wn = wave & 1;
    const int m16  = lane & 15, quad = lane >> 4;
    const int kq   = quad * 8;

    // A staging: 2 rows x 8 bf16 per thread per K-tile
    const int arow0 = t >> 2;
    const int arow1 = 64 + (t >> 2);
    const int acol  = (t & 3) * 8;
    const unsigned short *ap0, *ap1;
    if (MODE == 0) {
        int tok0 = slot_token[off + mt * 128 + arow0];  // partial-tile reads land in
        int tok1 = slot_token[off + mt * 128 + arow1];  // neighbor/shared region: defined, discarded
        ap0 = Abase + (size_t)tok0 * lda + acol;
        ap1 = Abase + (size_t)tok1 * lda + acol;
    } else {
        ap0 = Abase + (size_t)(off + mt * 128 + arow0) * lda + acol;
        ap1 = Abase + (size_t)(off + mt * 128 + arow1) * lda + acol;
    }

    // B staging: transpose-in-register, wave-coalesced float2 loads along n
    const int bn  = (t & 63) * 2;   // 0..126
    const int bkh = t >> 6;         // 0..3 -> k-subgroup of 8
    const float* bp = Bp + (size_t)(bkh * 8) * Nn + nt * 128 + bn;

    floatx4 acc[4][4];
    #pragma unroll
    for (int i = 0; i < 4; ++i)
        #pragma unroll
        for (int j = 0; j < 4; ++j)
            acc[i][j] = (floatx4){0.f, 0.f, 0.f, 0.f};

    const int nK = K / 32;
    for (int kt = 0; kt < nK; ++kt) {
        us8 a0 = *(const us8*)(ap0 + kt * 32);
        us8 a1 = *(const us8*)(ap1 + kt * 32);
        const float* bpk = bp + (size_t)kt * 32 * Nn;
        float2 bv[8];
        #pragma unroll
        for (int kk = 0; kk < 8; ++kk)
            bv[kk] = *(const float2*)(bpk + (size_t)kk * Nn);

        us8 c0, c1;
        #pragma unroll
        for (int kk = 0; kk < 8; ++kk) {
            c0[kk] = f2bf(bv[kk].x);
            c1[kk] = f2bf(bv[kk].y);
        }

        *(us8*)&As[arow0 * 40 + acol] = a0;
        *(us8*)&As[arow1 * 40 + acol] = a1;
        *(us8*)&Bs[bn * 40 + bkh * 8] = c0;        // Bs[n][k] = B[k][n]
        *(us8*)&Bs[(bn + 1) * 40 + bkh * 8] = c1;
        __syncthreads();

        bf16x8 af[4], bfr[4];
        #pragma unroll
        for (int i = 0; i < 4; ++i)
            af[i] = *(const bf16x8*)&As[(wm * 64 + i * 16 + m16) * 40 + kq];
        #pragma unroll
        for (int j = 0; j < 4; ++j)
            bfr[j] = *(const bf16x8*)&Bs[(wn * 64 + j * 16 + m16) * 40 + kq];
        #pragma unroll
        for (int i = 0; i < 4; ++i)
            #pragma unroll
            for (int j = 0; j < 4; ++j)
                acc[i][j] = __builtin_amdgcn_mfma_f32_16x16x32_bf16(af[i], bfr[j], acc[i][j], 0, 0, 0);
        __syncthreads();
    }

    // epilogue: C/D layout col = lane&15, row = quad*4 + reg  [m89-verified]
    const int gn0 = nt * 128 + wn * 64 + m16;
    #pragma unroll
    for (int i = 0; i < 4; ++i) {
        const int lmb = mt * 128 + wm * 64 + i * 16 + quad * 4;
        #pragma unroll
        for (int r = 0; r < 4; ++r) {
            const int lm = lmb + r;
            if (lm < cnt) {                     // guard: never clobber next expert's rows
                size_t ro = (size_t)(off + lm) * Nn;
                if (MODE == 0) {
                    #pragma unroll
                    for (int j = 0; j < 4; ++j) {
                        float v = acc[i][j][r];
                        v = v > 0.f ? v * v : 0.f;     // sq_relu
                        Hout[ro + gn0 + j * 16] = f2bf(v);
                    }
                } else {
                    float w = slot_w[off + lm];
                    #pragma unroll
                    for (int j = 0; j < 4; ++j)
                        Yout[ro + gn0 + j * 16] = w * acc[i][j][r];
                }
            }
        }
    }
}

// ---------------- combine: out[t] = yg[s0] + yg[s1] + yg[shared(t)] ----------------
__global__ void combine_kernel(const float* __restrict__ yg, const int* __restrict__ token_slot,
                               float* __restrict__ out) {
    int idx = blockIdx.x * 256 + threadIdx.x;   // float4 index; 256 float4 per token row
    int t = idx >> 8;
    int c = idx & 255;
    int s0 = token_slot[t * 2], s1 = token_slot[t * 2 + 1];
    const float4* y4 = (const float4*)yg;
    float4 a = y4[(size_t)s0 * 256 + c];
    float4 b = y4[(size_t)s1 * 256 + c];
    float4 d = y4[(size_t)(NSLOT + t) * 256 + c];
    float4 o;
    o.x = a.x + b.x + d.x;
    o.y = a.y + b.y + d.y;
    o.z = a.z + b.z + d.z;
    o.w = a.w + b.w + d.w;
    *((float4*)out + idx) = o;
}

extern "C" void kernel_launch(void* const* d_in, const int* in_sizes, int n_in,
                              void* d_out, int out_size, void* d_ws, size_t ws_size,
                              hipStream_t stream) {
    const float* x       = (const float*)d_in[0];
    const float* Wr      = (const float*)d_in[1];
    const float* Wup     = (const float*)d_in[2];
    const float* Wdown   = (const float*)d_in[3];
    const float* Wshup   = (const float*)d_in[4];
    const float* Wshdown = (const float*)d_in[5];
    float* out = (float*)d_out;

    char* ws = (char*)d_ws;
    unsigned short* xb = (unsigned short*)ws;                    // 4096*1024*2      = 8,388,608
    unsigned short* hg = (unsigned short*)(ws + 8388608);        // 12288*4096*2     = 100,663,296
    float* yg          = (float*)(ws + 109051904);               // 12288*1024*4     = 50,331,648
    char* meta         = ws + 159383552;
    int*   counts      = (int*)meta;                             // 64 B  (zeroed)
    int*   cursors     = (int*)(meta + 64);                      // 64 B  (zeroed)
    int*   offsets     = (int*)(meta + 128);                     // 64 B
    int*   topk_idx    = (int*)(meta + 256);                     // 32 KB
    float* topk_w      = (float*)(meta + 256 + 32768);           // 32 KB
    int*   token_slot  = (int*)(meta + 256 + 65536);             // 32 KB
    int*   slot_token  = (int*)(meta + 256 + 98304);             // 48 KB
    float* slot_w      = (float*)(meta + 256 + 98304 + 49152);   // 48 KB

    hipMemsetAsync(meta, 0, 128, stream);
    cvt_x_kernel<<<4096, 256, 0, stream>>>(x, xb);
    router_kernel<<<1024, 256, 0, stream>>>(x, Wr, topk_idx, topk_w, counts);
    scan_kernel<<<1, 64, 0, stream>>>(counts, offsets);
    assign_kernel<<<16, 256, 0, stream>>>(topk_idx, topk_w, offsets, cursors,
                                          slot_token, slot_w, token_slot);
    // up: [cnt_e,1024] x [1024,4096] -> hg (sq_relu, bf16); expert 8 = shared
    moe_gemm<0><<<dim3(32, 32, 9), 256, 0, stream>>>(xb, Wup, Wshup, hg, yg,
                                                     slot_token, slot_w, counts, offsets,
                                                     1024, 4096, 1024);
    // down: [cnt_e,4096] x [4096,1024] -> yg (weighted, fp32)
    moe_gemm<1><<<dim3(8, 32, 9), 256, 0, stream>>>(hg, Wdown, Wshdown, hg, yg,
                                                    slot_token, slot_w, counts, offsets,
                                                    4096, 1024, 4096);
    combine_kernel<<<4096, 256, 0, stream>>>(yg, token_slot, out);
}

// Round 2
// 807.868 us; speedup vs baseline: 1.1185x; 1.1185x over previous
//
#include <hip/hip_runtime.h>

#define N_TOK 4096
#define DIM   1024
#define HID   4096
#define NSLOT 8192          // N_TOK * TOPK
#define TOTROWS 12288       // NSLOT + N_TOK (shared expert appended)

typedef __bf16 bf16x8 __attribute__((ext_vector_type(8)));
typedef float  floatx4 __attribute__((ext_vector_type(4)));
typedef unsigned short us8 __attribute__((ext_vector_type(8)));
typedef unsigned short us4v __attribute__((ext_vector_type(4)));

static __device__ __forceinline__ unsigned short f2bf(float f) {
    unsigned u = __builtin_bit_cast(unsigned, f);
    unsigned r = 0x7fffu + ((u >> 16) & 1u);
    return (unsigned short)((u + r) >> 16);
}

// async global->LDS, 16B per lane; LDS dest = wave-uniform base + lane*16
static __device__ __forceinline__ void async16(const unsigned short* g, unsigned short* l) {
    __builtin_amdgcn_global_load_lds(
        (const __attribute__((address_space(1))) void*)g,
        (__attribute__((address_space(3))) void*)l,
        16, 0, 0);
}

// ---------------- x -> bf16 ----------------
__global__ void cvt_x_kernel(const float* __restrict__ x, unsigned short* __restrict__ xb) {
    int i = (blockIdx.x * 256 + threadIdx.x) * 4;
    float4 v = *(const float4*)(x + i);
    us4v o; o[0] = f2bf(v.x); o[1] = f2bf(v.y); o[2] = f2bf(v.z); o[3] = f2bf(v.w);
    *(us4v*)(xb + i) = o;
}

// ---------------- router: fp64 logits, top-2, counts ----------------
__global__ void router_kernel(const float* __restrict__ x, const float* __restrict__ Wr,
                              int* __restrict__ topk_idx, float* __restrict__ topk_w,
                              int* __restrict__ counts) {
    int lane = threadIdx.x & 63;
    int wave = threadIdx.x >> 6;
    int t = blockIdx.x * 4 + wave;
    const float* xr = x + (size_t)t * DIM;
    double acc[8];
    #pragma unroll
    for (int e = 0; e < 8; ++e) acc[e] = 0.0;
    #pragma unroll
    for (int it = 0; it < DIM / 64; ++it) {
        int d = it * 64 + lane;
        float xv = xr[d];
        const float* wr = Wr + (size_t)d * 8;
        float4 w0 = *(const float4*)wr;
        float4 w1 = *(const float4*)(wr + 4);
        acc[0] += (double)xv * w0.x; acc[1] += (double)xv * w0.y;
        acc[2] += (double)xv * w0.z; acc[3] += (double)xv * w0.w;
        acc[4] += (double)xv * w1.x; acc[5] += (double)xv * w1.y;
        acc[6] += (double)xv * w1.z; acc[7] += (double)xv * w1.w;
    }
    #pragma unroll
    for (int e = 0; e < 8; ++e) {
        #pragma unroll
        for (int off = 32; off > 0; off >>= 1)
            acc[e] += __shfl_xor(acc[e], off, 64);
    }
    if (lane == 0) {
        float p[8];
        #pragma unroll
        for (int e = 0; e < 8; ++e) p[e] = 1.0f / (1.0f + expf(-(float)acc[e]));
        int i0 = 0;
        for (int e = 1; e < 8; ++e) if (p[e] > p[i0]) i0 = e;        // ties -> lower idx
        int i1 = (i0 == 0) ? 1 : 0;
        for (int e = 0; e < 8; ++e) if (e != i0 && p[e] > p[i1]) i1 = e;
        float s = p[i0] + p[i1] + 1e-6f;
        topk_idx[t * 2]     = i0;
        topk_idx[t * 2 + 1] = i1;
        topk_w[t * 2]       = p[i0] / s;
        topk_w[t * 2 + 1]   = p[i1] / s;
        atomicAdd(&counts[i0], 1);
        atomicAdd(&counts[i1], 1);
    }
}

// ---------------- tiny exclusive scan over 8 experts ----------------
__global__ void scan_kernel(const int* __restrict__ counts, int* __restrict__ offsets) {
    if (threadIdx.x == 0) {
        int off = 0;
        for (int e = 0; e < 8; ++e) { offsets[e] = off; off += counts[e]; }
        offsets[8] = off;   // == NSLOT
    }
}

// ---------------- slot assignment (compacted per-expert lists) ----------------
__global__ void assign_kernel(const int* __restrict__ topk_idx, const float* __restrict__ topk_w,
                              const int* __restrict__ offsets, int* __restrict__ cursors,
                              int* __restrict__ slot_token, float* __restrict__ slot_w,
                              int* __restrict__ token_slot) {
    int t = blockIdx.x * 256 + threadIdx.x;
    #pragma unroll
    for (int j = 0; j < 2; ++j) {
        int e = topk_idx[t * 2 + j];
        int pos = atomicAdd(&cursors[e], 1);
        int s = offsets[e] + pos;
        slot_token[s] = t;
        slot_w[s] = topk_w[t * 2 + j];
        token_slot[t * 2 + j] = s;
    }
    // shared expert = "expert 8": all tokens, weight 1
    slot_token[NSLOT + t] = t;
    slot_w[NSLOT + t] = 1.0f;
}

// ---------------- transpose + cvt: in fp32 [R][C] -> out bf16 [C][R], z=expert (8=shared) --------
__global__ void transpose_cvt(const float* __restrict__ Wexp, const float* __restrict__ Wsh,
                              unsigned short* __restrict__ outbuf, int R, int C) {
    const int z = blockIdx.z;
    const float* in = (z < 8) ? (Wexp + (size_t)z * R * C) : Wsh;
    unsigned short* out = outbuf + (size_t)z * (size_t)R * C;
    __shared__ float tile[64][65];
    const int t   = threadIdx.x;
    const int tr  = t >> 4;         // 0..15
    const int tc4 = (t & 15) * 4;   // 0..60
    const int gr0 = blockIdx.y * 64;
    const int gc0 = blockIdx.x * 64;
    #pragma unroll
    for (int i = 0; i < 4; ++i) {
        int r = i * 16 + tr;
        float4 v = *(const float4*)(in + (size_t)(gr0 + r) * C + gc0 + tc4);
        tile[r][tc4 + 0] = v.x; tile[r][tc4 + 1] = v.y;
        tile[r][tc4 + 2] = v.z; tile[r][tc4 + 3] = v.w;
    }
    __syncthreads();
    #pragma unroll
    for (int i = 0; i < 4; ++i) {
        int c = i * 16 + tr;        // out row = global col
        us4v o;
        #pragma unroll
        for (int j = 0; j < 4; ++j) o[j] = f2bf(tile[tc4 + j][c]);
        *(us4v*)(out + (size_t)(gc0 + c) * R + gr0 + tc4) = o;
    }
}

// ---------------- grouped GEMM (async staging, pre-transposed bf16 B) ----------------
// MODE 0: up   — A = xb gathered via slot_token, epilogue sq_relu, bf16 out (hg)
// MODE 1: down — A = hg rows direct, epilogue *slot_w, fp32 out (yg)
// Wt layout: [9][Nn][K] bf16 (expert 8 = shared)
template<int MODE>
__global__ void moe_gemm_a(const unsigned short* __restrict__ Abase,
                           const unsigned short* __restrict__ Wt,
                           unsigned short* __restrict__ Hout,
                           float* __restrict__ Yout,
                           const int* __restrict__ slot_token,
                           const float* __restrict__ slot_w,
                           const int* __restrict__ counts,
                           const int* __restrict__ offsets,
                           int K, int Nn, int lda)
{
    const int e   = blockIdx.z;
    const int cnt = (e == 8) ? N_TOK : counts[e];
    const int mt  = blockIdx.y;
    if (mt * 128 >= cnt) return;            // uniform early-exit (worst-case grid)
    const int nt  = blockIdx.x;
    const int off = offsets[e];

    __shared__ unsigned short As[128 * 32];   // unpadded: required by global_load_lds
    __shared__ unsigned short Bs[128 * 32];

    const int t    = threadIdx.x;
    const int lane = t & 63;
    const int wave = t >> 6;

    // staging: wave w covers 1KiB chunks {2w, 2w+1} of each tile.
    // chunk c = rows [c*16, c*16+16); lane l -> row c*16 + l/4, k-chunk (l&3)*8
    const unsigned short* agp[2];
    const unsigned short* bgp[2];
    unsigned short* aldst[2];
    unsigned short* bldst[2];
    #pragma unroll
    for (int q = 0; q < 2; ++q) {
        const int c   = wave * 2 + q;
        const int row = c * 16 + (lane >> 2);
        const int kc  = (lane & 3) * 8;
        int arow;
        if (MODE == 0) arow = slot_token[off + mt * 128 + row];  // partial-tile rows land in
        else           arow = off + mt * 128 + row;              // neighbor/shared region: defined, discarded
        agp[q]   = Abase + (size_t)arow * lda + kc;
        bgp[q]   = Wt + (size_t)e * Nn * K + (size_t)(nt * 128 + row) * K + kc;
        aldst[q] = &As[c * 512];
        bldst[q] = &Bs[c * 512];
    }

    const int wm  = wave >> 1, wn = wave & 1;
    const int m16 = lane & 15, quad = lane >> 4;
    const int kq  = quad * 8;

    floatx4 acc[4][4];
    #pragma unroll
    for (int i = 0; i < 4; ++i)
        #pragma unroll
        for (int j = 0; j < 4; ++j)
            acc[i][j] = (floatx4){0.f, 0.f, 0.f, 0.f};

    const int nK = K / 32;
    for (int kt = 0; kt < nK; ++kt) {
        const int ko = kt * 32;
        #pragma unroll
        for (int q = 0; q < 2; ++q) {
            async16(agp[q] + ko, aldst[q]);
            async16(bgp[q] + ko, bldst[q]);
        }
        __syncthreads();     // drains vmcnt (global_load_lds) per m97

        bf16x8 af[4], bfr[4];
        #pragma unroll
        for (int i = 0; i < 4; ++i)
            af[i] = *(const bf16x8*)&As[(wm * 64 + i * 16 + m16) * 32 + kq];
        #pragma unroll
        for (int j = 0; j < 4; ++j)
            bfr[j] = *(const bf16x8*)&Bs[(wn * 64 + j * 16 + m16) * 32 + kq];
        #pragma unroll
        for (int i = 0; i < 4; ++i)
            #pragma unroll
            for (int j = 0; j < 4; ++j)
                acc[i][j] = __builtin_amdgcn_mfma_f32_16x16x32_bf16(af[i], bfr[j], acc[i][j], 0, 0, 0);
        __syncthreads();
    }

    // epilogue: C/D layout col = lane&15, row = quad*4 + reg  [m89-verified]
    const int gn0 = nt * 128 + wn * 64 + m16;
    #pragma unroll
    for (int i = 0; i < 4; ++i) {
        const int lmb = mt * 128 + wm * 64 + i * 16 + quad * 4;
        #pragma unroll
        for (int r = 0; r < 4; ++r) {
            const int lm = lmb + r;
            if (lm < cnt) {                     // guard: never clobber next expert's rows
                size_t ro = (size_t)(off + lm) * Nn;
                if (MODE == 0) {
                    #pragma unroll
                    for (int j = 0; j < 4; ++j) {
                        float v = acc[i][j][r];
                        v = v > 0.f ? v * v : 0.f;     // sq_relu
                        Hout[ro + gn0 + j * 16] = f2bf(v);
                    }
                } else {
                    float w = slot_w[off + lm];
                    #pragma unroll
                    for (int j = 0; j < 4; ++j)
                        Yout[ro + gn0 + j * 16] = w * acc[i][j][r];
                }
            }
        }
    }
}

// ---------------- fallback GEMM (round-1, fp32 B staged in-register) ----------------
template<int MODE>
__global__ void moe_gemm_fb(const unsigned short* __restrict__ Abase,
                            const float* __restrict__ Wexp,
                            const float* __restrict__ Wsh,
                            unsigned short* __restrict__ Hout,
                            float* __restrict__ Yout,
                            const int* __restrict__ slot_token,
                            const float* __restrict__ slot_w,
                            const int* __restrict__ counts,
                            const int* __restrict__ offsets,
                            int K, int Nn, int lda)
{
    const int e   = blockIdx.z;
    const int cnt = (e == 8) ? N_TOK : counts[e];
    const int mt  = blockIdx.y;
    if (mt * 128 >= cnt) return;
    const int nt  = blockIdx.x;
    const int off = offsets[e];
    const float* Bp = (e == 8) ? Wsh : (Wexp + (size_t)e * K * Nn);

    __shared__ unsigned short As[128 * 40];
    __shared__ unsigned short Bs[128 * 40];

    const int t    = threadIdx.x;
    const int lane = t & 63;
    const int wave = t >> 6;
    const int wm   = wave >> 1, wn = wave & 1;
    const int m16  = lane & 15, quad = lane >> 4;
    const int kq   = quad * 8;

    const int arow0 = t >> 2;
    const int arow1 = 64 + (t >> 2);
    const int acol  = (t & 3) * 8;
    const unsigned short *ap0, *ap1;
    if (MODE == 0) {
        int tok0 = slot_token[off + mt * 128 + arow0];
        int tok1 = slot_token[off + mt * 128 + arow1];
        ap0 = Abase + (size_t)tok0 * lda + acol;
        ap1 = Abase + (size_t)tok1 * lda + acol;
    } else {
        ap0 = Abase + (size_t)(off + mt * 128 + arow0) * lda + acol;
        ap1 = Abase + (size_t)(off + mt * 128 + arow1) * lda + acol;
    }

    const int bn  = (t & 63) * 2;
    const int bkh = t >> 6;
    const float* bp = Bp + (size_t)(bkh * 8) * Nn + nt * 128 + bn;

    floatx4 acc[4][4];
    #pragma unroll
    for (int i = 0; i < 4; ++i)
        #pragma unroll
        for (int j = 0; j < 4; ++j)
            acc[i][j] = (floatx4){0.f, 0.f, 0.f, 0.f};

    const int nK = K / 32;
    for (int kt = 0; kt < nK; ++kt) {
        us8 a0 = *(const us8*)(ap0 + kt * 32);
        us8 a1 = *(const us8*)(ap1 + kt * 32);
        const float* bpk = bp + (size_t)kt * 32 * Nn;
        float2 bv[8];
        #pragma unroll
        for (int kk = 0; kk < 8; ++kk)
            bv[kk] = *(const float2*)(bpk + (size_t)kk * Nn);

        us8 c0, c1;
        #pragma unroll
        for (int kk = 0; kk < 8; ++kk) {
            c0[kk] = f2bf(bv[kk].x);
            c1[kk] = f2bf(bv[kk].y);
        }

        *(us8*)&As[arow0 * 40 + acol] = a0;
        *(us8*)&As[arow1 * 40 + acol] = a1;
        *(us8*)&Bs[bn * 40 + bkh * 8] = c0;
        *(us8*)&Bs[(bn + 1) * 40 + bkh * 8] = c1;
        __syncthreads();

        bf16x8 af[4], bfr[4];
        #pragma unroll
        for (int i = 0; i < 4; ++i)
            af[i] = *(const bf16x8*)&As[(wm * 64 + i * 16 + m16) * 40 + kq];
        #pragma unroll
        for (int j = 0; j < 4; ++j)
            bfr[j] = *(const bf16x8*)&Bs[(wn * 64 + j * 16 + m16) * 40 + kq];
        #pragma unroll
        for (int i = 0; i < 4; ++i)
            #pragma unroll
            for (int j = 0; j < 4; ++j)
                acc[i][j] = __builtin_amdgcn_mfma_f32_16x16x32_bf16(af[i], bfr[j], acc[i][j], 0, 0, 0);
        __syncthreads();
    }

    const int gn0 = nt * 128 + wn * 64 + m16;
    #pragma unroll
    for (int i = 0; i < 4; ++i) {
        const int lmb = mt * 128 + wm * 64 + i * 16 + quad * 4;
        #pragma unroll
        for (int r = 0; r < 4; ++r) {
            const int lm = lmb + r;
            if (lm < cnt) {
                size_t ro = (size_t)(off + lm) * Nn;
                if (MODE == 0) {
                    #pragma unroll
                    for (int j = 0; j < 4; ++j) {
                        float v = acc[i][j][r];
                        v = v > 0.f ? v * v : 0.f;
                        Hout[ro + gn0 + j * 16] = f2bf(v);
                    }
                } else {
                    float w = slot_w[off + lm];
                    #pragma unroll
                    for (int j = 0; j < 4; ++j)
                        Yout[ro + gn0 + j * 16] = w * acc[i][j][r];
                }
            }
        }
    }
}

// ---------------- combine: out[t] = yg[s0] + yg[s1] + yg[shared(t)] ----------------
__global__ void combine_kernel(const float* __restrict__ yg, const int* __restrict__ token_slot,
                               float* __restrict__ out) {
    int idx = blockIdx.x * 256 + threadIdx.x;   // float4 index; 256 float4 per token row
    int t = idx >> 8;
    int c = idx & 255;
    int s0 = token_slot[t * 2], s1 = token_slot[t * 2 + 1];
    const float4* y4 = (const float4*)yg;
    float4 a = y4[(size_t)s0 * 256 + c];
    float4 b = y4[(size_t)s1 * 256 + c];
    float4 d = y4[(size_t)(NSLOT + t) * 256 + c];
    float4 o;
    o.x = a.x + b.x + d.x;
    o.y = a.y + b.y + d.y;
    o.z = a.z + b.z + d.z;
    o.w = a.w + b.w + d.w;
    *((float4*)out + idx) = o;
}

extern "C" void kernel_launch(void* const* d_in, const int* in_sizes, int n_in,
                              void* d_out, int out_size, void* d_ws, size_t ws_size,
                              hipStream_t stream) {
    const float* x       = (const float*)d_in[0];
    const float* Wr      = (const float*)d_in[1];
    const float* Wup     = (const float*)d_in[2];
    const float* Wdown   = (const float*)d_in[3];
    const float* Wshup   = (const float*)d_in[4];
    const float* Wshdown = (const float*)d_in[5];
    float* out = (float*)d_out;
    char* ws = (char*)d_ws;

    // primary layout (needs 227 MB):
    //   hg   [0, 100663296)                      12288*4096 bf16
    //   Wt   [100663296, 176160768)              9*4096*1024 bf16 — Wut during up, Wdt during down
    //   xb/yg[176160768, 226492416)              xb (8.4MB, dead after up) aliased under yg (50.3MB)
    //   meta [226492416, ...)
    const size_t NEEDED = 226492416ull + 262144ull;

    if (ws_size >= NEEDED) {
        unsigned short* hg = (unsigned short*)ws;
        unsigned short* Wt = (unsigned short*)(ws + 100663296);
        unsigned short* xb = (unsigned short*)(ws + 176160768);
        float*          yg = (float*)(ws + 176160768);
        char* meta         = ws + 226492416;
        int*   counts      = (int*)meta;
        int*   cursors     = (int*)(meta + 64);
        int*   offsets     = (int*)(meta + 128);
        int*   topk_idx    = (int*)(meta + 256);
        float* topk_w      = (float*)(meta + 256 + 32768);
        int*   token_slot  = (int*)(meta + 256 + 65536);
        int*   slot_token  = (int*)(meta + 256 + 98304);
        float* slot_w      = (float*)(meta + 256 + 98304 + 49152);

        hipMemsetAsync(meta, 0, 128, stream);
        cvt_x_kernel<<<4096, 256, 0, stream>>>(x, xb);
        router_kernel<<<1024, 256, 0, stream>>>(x, Wr, topk_idx, topk_w, counts);
        scan_kernel<<<1, 64, 0, stream>>>(counts, offsets);
        assign_kernel<<<16, 256, 0, stream>>>(topk_idx, topk_w, offsets, cursors,
                                              slot_token, slot_w, token_slot);
        // W_up [e][1024][4096] -> Wt [e][4096][1024] bf16
        transpose_cvt<<<dim3(64, 16, 9), 256, 0, stream>>>(Wup, Wshup, Wt, 1024, 4096);
        // up: [cnt_e,1024] x Wt[e] -> hg (sq_relu, bf16)
        moe_gemm_a<0><<<dim3(32, 32, 9), 256, 0, stream>>>(xb, Wt, hg, yg,
                                                           slot_token, slot_w, counts, offsets,
                                                           1024, 4096, 1024);
        // W_down [e][4096][1024] -> Wt [e][1024][4096] bf16 (overwrites Wut — up done)
        transpose_cvt<<<dim3(16, 64, 9), 256, 0, stream>>>(Wdown, Wshdown, Wt, 4096, 1024);
        // down: [cnt_e,4096] x Wt[e] -> yg (weighted, fp32)
        moe_gemm_a<1><<<dim3(8, 32, 9), 256, 0, stream>>>(hg, Wt, hg, yg,
                                                          slot_token, slot_w, counts, offsets,
                                                          4096, 1024, 4096);
        combine_kernel<<<4096, 256, 0, stream>>>(yg, token_slot, out);
    } else {
        // fallback: round-1 path (159.6 MB)
        unsigned short* xb = (unsigned short*)ws;
        unsigned short* hg = (unsigned short*)(ws + 8388608);
        float* yg          = (float*)(ws + 109051904);
        char* meta         = ws + 159383552;
        int*   counts      = (int*)meta;
        int*   cursors     = (int*)(meta + 64);
        int*   offsets     = (int*)(meta + 128);
        int*   topk_idx    = (int*)(meta + 256);
        float* topk_w      = (float*)(meta + 256 + 32768);
        int*   token_slot  = (int*)(meta + 256 + 65536);
        int*   slot_token  = (int*)(meta + 256 + 98304);
        float* slot_w      = (float*)(meta + 256 + 98304 + 49152);

        hipMemsetAsync(meta, 0, 128, stream);
        cvt_x_kernel<<<4096, 256, 0, stream>>>(x, xb);
        router_kernel<<<1024, 256, 0, stream>>>(x, Wr, topk_idx, topk_w, counts);
        scan_kernel<<<1, 64, 0, stream>>>(counts, offsets);
        assign_kernel<<<16, 256, 0, stream>>>(topk_idx, topk_w, offsets, cursors,
                                              slot_token, slot_w, token_slot);
        moe_gemm_fb<0><<<dim3(32, 32, 9), 256, 0, stream>>>(xb, Wup, Wshup, hg, yg,
                                                            slot_token, slot_w, counts, offsets,
                                                            1024, 4096, 1024);
        moe_gemm_fb<1><<<dim3(8, 32, 9), 256, 0, stream>>>(hg, Wdown, Wshdown, hg, yg,
                                                           slot_token, slot_w, counts, offsets,
                                                           4096, 1024, 4096);
        combine_kernel<<<4096, 256, 0, stream>>>(yg, token_slot, out);
    }
}